// Round 4
// baseline (570.671 us; speedup 1.0000x reference)
//
#include <hip/hip_runtime.h>
#include <stdint.h>

#define N_NODES 20000
#define E_EDGES 320000
#define H_DIM 128
#define A_DIM 512
#define NEMB_N 400
#define K_SEL 80000u
#define NB1 16384
#define NB2 16384
#define CAND_MAX 8192
#define LO_F (-128.0f)
#define SCALE1 (16384.0f / 160.0f)   /* bins over [-128, 32) */
#define KN_M 32                      /* k_node tile: 32 nodes */

struct SelState {
    int b1; unsigned cum1; unsigned r1;
    int b2; unsigned cum2; unsigned r2;
    unsigned long long T;
};

// ---------------- threefry2x32 (JAX, 20 rounds) ----------------
__device__ __forceinline__ uint32_t rotl32(uint32_t x, int r) {
    return (x << r) | (x >> (32 - r));
}

__device__ __forceinline__ void threefry2x32(uint32_t k0, uint32_t k1,
                                             uint32_t& x0, uint32_t& x1) {
    uint32_t ks0 = k0, ks1 = k1, ks2 = k0 ^ k1 ^ 0x1BD11BDAu;
    x0 += ks0; x1 += ks1;
    x0 += x1; x1 = rotl32(x1, 13); x1 ^= x0;
    x0 += x1; x1 = rotl32(x1, 15); x1 ^= x0;
    x0 += x1; x1 = rotl32(x1, 26); x1 ^= x0;
    x0 += x1; x1 = rotl32(x1, 6);  x1 ^= x0;
    x0 += ks1; x1 += ks2 + 1u;
    x0 += x1; x1 = rotl32(x1, 17); x1 ^= x0;
    x0 += x1; x1 = rotl32(x1, 29); x1 ^= x0;
    x0 += x1; x1 = rotl32(x1, 16); x1 ^= x0;
    x0 += x1; x1 = rotl32(x1, 24); x1 ^= x0;
    x0 += ks2; x1 += ks0 + 2u;
    x0 += x1; x1 = rotl32(x1, 13); x1 ^= x0;
    x0 += x1; x1 = rotl32(x1, 15); x1 ^= x0;
    x0 += x1; x1 = rotl32(x1, 26); x1 ^= x0;
    x0 += x1; x1 = rotl32(x1, 6);  x1 ^= x0;
    x0 += ks0; x1 += ks1 + 3u;
    x0 += x1; x1 = rotl32(x1, 17); x1 ^= x0;
    x0 += x1; x1 = rotl32(x1, 29); x1 ^= x0;
    x0 += x1; x1 = rotl32(x1, 16); x1 ^= x0;
    x0 += x1; x1 = rotl32(x1, 24); x1 ^= x0;
    x0 += ks1; x1 += ks2 + 4u;
    x0 += x1; x1 = rotl32(x1, 13); x1 ^= x0;
    x0 += x1; x1 = rotl32(x1, 15); x1 ^= x0;
    x0 += x1; x1 = rotl32(x1, 26); x1 ^= x0;
    x0 += x1; x1 = rotl32(x1, 6);  x1 ^= x0;
    x0 += ks2; x1 += ks0 + 5u;
}

// ---------- k_node v3: register-tiled (TM=8 x TN=4), M=32 nodes/block ----
// LDS holds transposed operand [dim][node] with +4 pad (16B-aligned rows).
// Per k: 2x ds_read_b128 (8 nodes) + 4 weight dwords -> 32 FMA.
__global__ __launch_bounds__(128) void k_node(
    const float* __restrict__ x, const float* __restrict__ aerial,
    const float* __restrict__ Wlin, const float* __restrict__ blin,
    const float* __restrict__ Wq, const float* __restrict__ bq,
    const float* __restrict__ Wv, const float* __restrict__ bv,
    float* __restrict__ xl32, float* __restrict__ q32, float* __restrict__ v32) {
    __shared__ float bufA[H_DIM][KN_M + 4];
    __shared__ float bufX[H_DIM][KN_M + 4];
    const int tid = threadIdx.x;
    const int mg = tid >> 5;          // node group 0..3
    const int jj = tid & 31;          // col base 0..31
    const int nb = mg * 8;
    const int n0 = blockIdx.x * KN_M;
    const int c0 = jj, c1 = jj + 32, c2 = jj + 64, c3 = jj + 96;

    // stage x tile transposed: thread tid = dim j
    for (int m = 0; m < KN_M; ++m)
        bufA[tid][m] = x[(size_t)(n0 + m) * H_DIM + tid];
    __syncthreads();

    // xl = x @ Wlin + blin
    float accL[4][8];
    {
        float b0 = blin[c0], b1 = blin[c1], b2 = blin[c2], b3 = blin[c3];
#pragma unroll
        for (int i = 0; i < 8; ++i) {
            accL[0][i] = b0; accL[1][i] = b1; accL[2][i] = b2; accL[3][i] = b3;
        }
    }
#pragma unroll 4
    for (int k = 0; k < H_DIM; ++k) {
        const float4 xa = *(const float4*)&bufA[k][nb];
        const float4 xb = *(const float4*)&bufA[k][nb + 4];
        const float w0 = Wlin[k * H_DIM + c0];
        const float w1 = Wlin[k * H_DIM + c1];
        const float w2 = Wlin[k * H_DIM + c2];
        const float w3 = Wlin[k * H_DIM + c3];
        const float xv[8] = {xa.x, xa.y, xa.z, xa.w, xb.x, xb.y, xb.z, xb.w};
#pragma unroll
        for (int i = 0; i < 8; ++i) {
            accL[0][i] = fmaf(xv[i], w0, accL[0][i]);
            accL[1][i] = fmaf(xv[i], w1, accL[1][i]);
            accL[2][i] = fmaf(xv[i], w2, accL[2][i]);
            accL[3][i] = fmaf(xv[i], w3, accL[3][i]);
        }
    }
    // write xl to global + stage transposed into bufX
#pragma unroll
    for (int c = 0; c < 4; ++c) {
        const int col = jj + c * 32;
#pragma unroll
        for (int i = 0; i < 8; ++i) {
            xl32[(size_t)(n0 + nb + i) * H_DIM + col] = accL[c][i];
            bufX[col][nb + i] = accL[c][i];
        }
    }
    __syncthreads();

    // v = xl @ Wv + bv  and  q (part 1) = xl @ Wq[0:128] + bq   (shared A reads)
    float accV[4][8], accQ[4][8];
    {
        float v0 = bv[c0], v1 = bv[c1], v2 = bv[c2], v3 = bv[c3];
        float q0 = bq[c0], q1 = bq[c1], q2 = bq[c2], q3 = bq[c3];
#pragma unroll
        for (int i = 0; i < 8; ++i) {
            accV[0][i] = v0; accV[1][i] = v1; accV[2][i] = v2; accV[3][i] = v3;
            accQ[0][i] = q0; accQ[1][i] = q1; accQ[2][i] = q2; accQ[3][i] = q3;
        }
    }
#pragma unroll 2
    for (int k = 0; k < H_DIM; ++k) {
        const float4 xa = *(const float4*)&bufX[k][nb];
        const float4 xb = *(const float4*)&bufX[k][nb + 4];
        const float wv0 = Wv[k * H_DIM + c0];
        const float wv1 = Wv[k * H_DIM + c1];
        const float wv2 = Wv[k * H_DIM + c2];
        const float wv3 = Wv[k * H_DIM + c3];
        const float wq0 = Wq[k * H_DIM + c0];
        const float wq1 = Wq[k * H_DIM + c1];
        const float wq2 = Wq[k * H_DIM + c2];
        const float wq3 = Wq[k * H_DIM + c3];
        const float xv[8] = {xa.x, xa.y, xa.z, xa.w, xb.x, xb.y, xb.z, xb.w};
#pragma unroll
        for (int i = 0; i < 8; ++i) {
            accV[0][i] = fmaf(xv[i], wv0, accV[0][i]);
            accV[1][i] = fmaf(xv[i], wv1, accV[1][i]);
            accV[2][i] = fmaf(xv[i], wv2, accV[2][i]);
            accV[3][i] = fmaf(xv[i], wv3, accV[3][i]);
            accQ[0][i] = fmaf(xv[i], wq0, accQ[0][i]);
            accQ[1][i] = fmaf(xv[i], wq1, accQ[1][i]);
            accQ[2][i] = fmaf(xv[i], wq2, accQ[2][i]);
            accQ[3][i] = fmaf(xv[i], wq3, accQ[3][i]);
        }
    }
#pragma unroll
    for (int c = 0; c < 4; ++c) {
        const int col = jj + c * 32;
#pragma unroll
        for (int i = 0; i < 8; ++i)
            v32[(size_t)(n0 + nb + i) * H_DIM + col] = accV[c][i];
    }

    // q (part 2): + aerial @ Wq[128:640], staged in 4 chunks of 128 dims
    for (int ch = 0; ch < 4; ++ch) {
        __syncthreads();
        for (int m = 0; m < KN_M; ++m)
            bufA[tid][m] = aerial[(size_t)(n0 + m) * A_DIM + ch * H_DIM + tid];
        __syncthreads();
        const float* Wqc = Wq + (size_t)(H_DIM + ch * H_DIM) * H_DIM;
#pragma unroll 4
        for (int k = 0; k < H_DIM; ++k) {
            const float4 xa = *(const float4*)&bufA[k][nb];
            const float4 xb = *(const float4*)&bufA[k][nb + 4];
            const float w0 = Wqc[k * H_DIM + c0];
            const float w1 = Wqc[k * H_DIM + c1];
            const float w2 = Wqc[k * H_DIM + c2];
            const float w3 = Wqc[k * H_DIM + c3];
            const float xv[8] = {xa.x, xa.y, xa.z, xa.w, xb.x, xb.y, xb.z, xb.w};
#pragma unroll
            for (int i = 0; i < 8; ++i) {
                accQ[0][i] = fmaf(xv[i], w0, accQ[0][i]);
                accQ[1][i] = fmaf(xv[i], w1, accQ[1][i]);
                accQ[2][i] = fmaf(xv[i], w2, accQ[2][i]);
                accQ[3][i] = fmaf(xv[i], w3, accQ[3][i]);
            }
        }
    }
#pragma unroll
    for (int c = 0; c < 4; ++c) {
        const int col = jj + c * 32;
#pragma unroll
        for (int i = 0; i < 8; ++i)
            q32[(size_t)(n0 + nb + i) * H_DIM + col] = accQ[c][i];
    }
}

// dist_q = dist_table @ Wq[640:768]   (no bias; bq folded into q_node)
__global__ __launch_bounds__(128) void k_dist(
    const float* __restrict__ dtab, const float* __restrict__ Wq,
    float* __restrict__ dq32) {
    __shared__ float dsT[H_DIM][8];
    const int j = threadIdx.x;
    const int n0 = blockIdx.x * 8;
#pragma unroll
    for (int m = 0; m < 8; ++m) dsT[j][m] = dtab[(size_t)(n0 + m) * H_DIM + j];
    __syncthreads();
    float acc[8];
#pragma unroll
    for (int m = 0; m < 8; ++m) acc[m] = 0.0f;
    for (int k = 0; k < H_DIM; ++k) {
        float w = Wq[(size_t)(H_DIM + A_DIM + k) * H_DIM + j];
        const float4* xp = (const float4*)&dsT[k][0];
        float4 a0 = xp[0], a1 = xp[1];
        acc[0] = fmaf(a0.x, w, acc[0]); acc[1] = fmaf(a0.y, w, acc[1]);
        acc[2] = fmaf(a0.z, w, acc[2]); acc[3] = fmaf(a0.w, w, acc[3]);
        acc[4] = fmaf(a1.x, w, acc[4]); acc[5] = fmaf(a1.y, w, acc[5]);
        acc[6] = fmaf(a1.z, w, acc[6]); acc[7] = fmaf(a1.w, w, acc[7]);
    }
#pragma unroll
    for (int m = 0; m < 8; ++m) dq32[(size_t)(n0 + m) * H_DIM + j] = acc[m];
}

__device__ __forceinline__ int bin1_of(float s) {
    float t = (s - LO_F) * SCALE1;
    int b = (int)t;
    return min(max(b, 0), NB1 - 1);
}
__device__ __forceinline__ int bin2_of(float s, int b1) {
    float t = (s - LO_F) * SCALE1;
    float frac = t - (float)b1;
    int b = (int)(frac * (float)NB2);
    return min(max(b, 0), NB2 - 1);
}

// ---------- per-edge score: 32 lanes per edge; fused threefry + hist1 ----
__global__ __launch_bounds__(256) void k_score(
    const int* __restrict__ ei, const int* __restrict__ dist,
    const float* __restrict__ q32, const float* __restrict__ v32,
    const float* __restrict__ dq32,
    unsigned long long* __restrict__ keys, float* __restrict__ s32o,
    unsigned* __restrict__ hist1) {
    const int half = threadIdx.x >> 5, lane = threadIdx.x & 31;
    const int e = blockIdx.x * 8 + half;
    const int s = ei[e], t = ei[E_EDGES + e];
    const int db = dist[e] / 50;
    const float4* qp = (const float4*)(q32 + (size_t)s * H_DIM);
    const float4* vp = (const float4*)(v32 + (size_t)t * H_DIM);
    const float4* dp = (const float4*)(dq32 + (size_t)db * H_DIM);
    float4 q = qp[lane], v = vp[lane], d = dp[lane];
    float dx = q.x + d.x - v.x;
    float dy = q.y + d.y - v.y;
    float dz = q.z + d.z - v.z;
    float dw = q.w + d.w - v.w;
    float ss = fmaf(dx, dx, fmaf(dy, dy, fmaf(dz, dz, dw * dw)));
#pragma unroll
    for (int o = 16; o > 0; o >>= 1) ss += __shfl_xor(ss, o, 64);
    // JAX partitionable threefry: counter=(0,e), key=(0,42), bits = out0^out1
    uint32_t r0 = 0u, r1 = (uint32_t)e;
    threefry2x32(0u, 42u, r0, r1);
    uint32_t fb = ((r0 ^ r1) >> 9) | 0x3f800000u;
    float uu = __uint_as_float(fb) - 1.0f;
    if (lane == 0) {
        float nrm = sqrtf(ss);
        float a = -logf(uu + 1e-20f);
        float g = -logf(a + 1e-20f);
        float score = g - nrm;
        int ib = __float_as_int(score);
        unsigned m32 = (ib < 0) ? ~(unsigned)ib : ((unsigned)ib | 0x80000000u);
        // unique key: score-ordered high bits, lower edge index wins ties
        keys[e] = ((unsigned long long)m32 << 32) | (unsigned)(0xFFFFFFFFu - (unsigned)e);
        s32o[e] = score;
        atomicAdd(&hist1[bin1_of(score)], 1u);
    }
}

__global__ __launch_bounds__(256) void k_hist2(const float* __restrict__ s32,
                                               const SelState* __restrict__ st,
                                               unsigned* __restrict__ hist2) {
    int e = blockIdx.x * 256 + threadIdx.x;
    if (e >= E_EDGES) return;
    float s = s32[e];
    int b1 = bin1_of(s);
    if (b1 != st->b1) return;
    atomicAdd(&hist2[bin2_of(s, b1)], 1u);
}

// descending scan over 16384 bins to locate the bin holding the target rank
__global__ __launch_bounds__(256) void k_scan(const unsigned* __restrict__ hist,
                                              SelState* st, int phase) {
    __shared__ unsigned csum[256];
    __shared__ unsigned bins[64];
    __shared__ int selc;
    __shared__ unsigned cumbase;
    const int t = threadIdx.x;
    const unsigned target = (phase == 1) ? K_SEL : st->r1;
    unsigned s = 0;
    for (int i = 0; i < 64; ++i) s += hist[t * 64 + i];
    csum[t] = s;
    __syncthreads();
    if (t == 0) {
        unsigned cum = 0; int c = 255;
        for (; c >= 0; --c) {
            if (cum + csum[c] >= target) break;
            cum += csum[c];
        }
        selc = c; cumbase = cum;
    }
    __syncthreads();
    if (t < 64) bins[t] = hist[selc * 64 + t];
    __syncthreads();
    if (t == 0) {
        unsigned cum = cumbase; int b = -1;
        for (int i = 63; i >= 0; --i) {
            if (cum + bins[i] >= target) { b = selc * 64 + i; break; }
            cum += bins[i];
        }
        unsigned r = target - cum;
        if (phase == 1) { st->b1 = b; st->cum1 = cum; st->r1 = r; }
        else           { st->b2 = b; st->cum2 = cum; st->r2 = r; }
    }
}

__global__ __launch_bounds__(256) void k_collect(
    const float* __restrict__ s32, const unsigned long long* __restrict__ keys,
    const SelState* __restrict__ st, unsigned long long* __restrict__ cand,
    unsigned* __restrict__ cnt) {
    int e = blockIdx.x * 256 + threadIdx.x;
    if (e >= E_EDGES) return;
    float s = s32[e];
    int b1 = bin1_of(s);
    if (b1 != st->b1) return;
    if (bin2_of(s, b1) != st->b2) return;
    unsigned p = atomicAdd(cnt, 1u);
    if (p < CAND_MAX) cand[p] = keys[e];
}

// T = r2-th largest key among candidates (keys are unique)
__global__ __launch_bounds__(256) void k_thresh(
    const unsigned long long* __restrict__ cand, const unsigned* __restrict__ cnt,
    SelState* st) {
    int c = (int)min(*cnt, (unsigned)CAND_MAX);
    unsigned r2 = st->r2;
    for (int i = threadIdx.x; i < c; i += blockDim.x) {
        unsigned long long ki = cand[i];
        unsigned g = 0;
        for (int j = 0; j < c; ++j) g += (cand[j] > ki);
        if (g == r2 - 1) st->T = ki;
    }
}

// wave per edge: key >= T selects; scatter xl[src] into msg[tgt] + deg
__global__ __launch_bounds__(256) void k_scatter(
    const int* __restrict__ ei, const unsigned long long* __restrict__ keys,
    const SelState* __restrict__ st, const float* __restrict__ xl32,
    float* __restrict__ msg, float* __restrict__ deg) {
    const int wid = threadIdx.x >> 6, lane = threadIdx.x & 63;
    const int e = blockIdx.x * 4 + wid;
    if (keys[e] >= st->T) {
        int sidx = ei[e], tidx = ei[E_EDGES + e];
        const float* xp = xl32 + (size_t)sidx * H_DIM;
        float* mp = msg + (size_t)tidx * H_DIM;
        const int h = lane * 2;
        atomicAdd(&mp[h], xp[h]);
        atomicAdd(&mp[h + 1], xp[h + 1]);
        if (lane == 0) atomicAdd(&deg[tidx], 1.0f);
    }
}

// out = (msg/max(deg,1)) @ Wl + bl + xl @ Wr
__global__ __launch_bounds__(128) void k_out(
    const float* __restrict__ msg, const float* __restrict__ deg,
    const float* __restrict__ xl32, const float* __restrict__ Wl,
    const float* __restrict__ bl, const float* __restrict__ Wr,
    float* __restrict__ out) {
    __shared__ float axT[H_DIM][8];
    __shared__ float xxT[H_DIM][8];
    const int j = threadIdx.x;
    const int n0 = blockIdx.x * 8;
#pragma unroll
    for (int m = 0; m < 8; ++m) {
        float d = fmaxf(deg[n0 + m], 1.0f);
        axT[j][m] = msg[(size_t)(n0 + m) * H_DIM + j] / d;
        xxT[j][m] = xl32[(size_t)(n0 + m) * H_DIM + j];
    }
    __syncthreads();
    float acc[8];
    float bj = bl[j];
#pragma unroll
    for (int m = 0; m < 8; ++m) acc[m] = bj;
    for (int k = 0; k < H_DIM; ++k) {
        float wl = Wl[k * H_DIM + j];
        float wr = Wr[k * H_DIM + j];
        const float4* ap = (const float4*)&axT[k][0];
        const float4* xp = (const float4*)&xxT[k][0];
        float4 a0 = ap[0], a1 = ap[1];
        float4 x0 = xp[0], x1 = xp[1];
        acc[0] = fmaf(a0.x, wl, fmaf(x0.x, wr, acc[0]));
        acc[1] = fmaf(a0.y, wl, fmaf(x0.y, wr, acc[1]));
        acc[2] = fmaf(a0.z, wl, fmaf(x0.z, wr, acc[2]));
        acc[3] = fmaf(a0.w, wl, fmaf(x0.w, wr, acc[3]));
        acc[4] = fmaf(a1.x, wl, fmaf(x1.x, wr, acc[4]));
        acc[5] = fmaf(a1.y, wl, fmaf(x1.y, wr, acc[5]));
        acc[6] = fmaf(a1.z, wl, fmaf(x1.z, wr, acc[6]));
        acc[7] = fmaf(a1.w, wl, fmaf(x1.w, wr, acc[7]));
    }
#pragma unroll
    for (int m = 0; m < 8; ++m) out[(size_t)(n0 + m) * H_DIM + j] = acc[m];
}

extern "C" void kernel_launch(void* const* d_in, const int* in_sizes, int n_in,
                              void* d_out, int out_size, void* d_ws, size_t ws_size,
                              hipStream_t stream) {
    const float* x      = (const float*)d_in[0];
    const int*   ei     = (const int*)d_in[1];
    const int*   dist   = (const int*)d_in[2];
    const float* aerial = (const float*)d_in[3];
    const float* Wlin   = (const float*)d_in[4];
    const float* blin   = (const float*)d_in[5];
    const float* Wq     = (const float*)d_in[6];
    const float* bq     = (const float*)d_in[7];
    const float* Wv     = (const float*)d_in[8];
    const float* bv     = (const float*)d_in[9];
    const float* dtab   = (const float*)d_in[10];
    const float* Wl     = (const float*)d_in[11];
    const float* bl     = (const float*)d_in[12];
    const float* Wr     = (const float*)d_in[13];
    float* out = (float*)d_out;

    char* ws = (char*)d_ws;
    size_t off = 0;
    auto alloc = [&](size_t bytes) -> void* {
        void* p = ws + off;
        off += (bytes + 255) & ~(size_t)255;
        return p;
    };
    float* q32  = (float*)alloc((size_t)N_NODES * H_DIM * 4);
    float* v32  = (float*)alloc((size_t)N_NODES * H_DIM * 4);
    float* dq32 = (float*)alloc((size_t)NEMB_N * H_DIM * 4);
    unsigned long long* keys = (unsigned long long*)alloc((size_t)E_EDGES * 8);
    float* xl32 = (float*)alloc((size_t)N_NODES * H_DIM * 4);
    float* s32  = (float*)alloc((size_t)E_EDGES * 4);
    char* zbase = ws + off;
    float* msg  = (float*)alloc((size_t)N_NODES * H_DIM * 4);
    float* deg  = (float*)alloc((size_t)N_NODES * 4);
    unsigned* hist1 = (unsigned*)alloc((size_t)NB1 * 4);
    unsigned* hist2 = (unsigned*)alloc((size_t)NB2 * 4);
    unsigned long long* cand = (unsigned long long*)alloc((size_t)CAND_MAX * 8);
    unsigned* counters = (unsigned*)alloc(256);   // [0]=candCount
    SelState* st = (SelState*)alloc(256);
    size_t zlen = (size_t)((ws + off) - zbase);

    hipMemsetAsync(zbase, 0, zlen, stream);

    k_node<<<N_NODES / KN_M, 128, 0, stream>>>(x, aerial, Wlin, blin, Wq, bq, Wv, bv,
                                               xl32, q32, v32);
    k_dist<<<NEMB_N / 8, 128, 0, stream>>>(dtab, Wq, dq32);
    k_score<<<E_EDGES / 8, 256, 0, stream>>>(ei, dist, q32, v32, dq32, keys, s32, hist1);
    k_scan<<<1, 256, 0, stream>>>(hist1, st, 1);
    k_hist2<<<(E_EDGES + 255) / 256, 256, 0, stream>>>(s32, st, hist2);
    k_scan<<<1, 256, 0, stream>>>(hist2, st, 2);
    k_collect<<<(E_EDGES + 255) / 256, 256, 0, stream>>>(s32, keys, st, cand, &counters[0]);
    k_thresh<<<1, 256, 0, stream>>>(cand, &counters[0], st);
    k_scatter<<<E_EDGES / 4, 256, 0, stream>>>(ei, keys, st, xl32, msg, deg);
    k_out<<<N_NODES / 8, 128, 0, stream>>>(msg, deg, xl32, Wl, bl, Wr, out);
}

// Round 6
// 499.255 us; speedup vs baseline: 1.1430x; 1.1430x over previous
//
#include <hip/hip_runtime.h>
#include <stdint.h>

#define N_NODES 20000
#define E_EDGES 320000
#define H_DIM 128
#define A_DIM 512
#define NEMB_N 400
#define K_SEL 80000u
#define NB1 16384
#define NB2 16384
#define CAND_MAX 8192
#define LO_F (-128.0f)
#define SCALE1 (16384.0f / 160.0f)   /* bins over [-128, 32) */
#define KN_M 32                      /* k_node tile: 32 nodes */

struct SelState {
    int b1; unsigned cum1; unsigned r1;
    int b2; unsigned cum2; unsigned r2;
    unsigned long long T;
};

// ---------------- threefry2x32 (JAX, 20 rounds) ----------------
__device__ __forceinline__ uint32_t rotl32(uint32_t x, int r) {
    return (x << r) | (x >> (32 - r));
}

__device__ __forceinline__ void threefry2x32(uint32_t k0, uint32_t k1,
                                             uint32_t& x0, uint32_t& x1) {
    uint32_t ks0 = k0, ks1 = k1, ks2 = k0 ^ k1 ^ 0x1BD11BDAu;
    x0 += ks0; x1 += ks1;
    x0 += x1; x1 = rotl32(x1, 13); x1 ^= x0;
    x0 += x1; x1 = rotl32(x1, 15); x1 ^= x0;
    x0 += x1; x1 = rotl32(x1, 26); x1 ^= x0;
    x0 += x1; x1 = rotl32(x1, 6);  x1 ^= x0;
    x0 += ks1; x1 += ks2 + 1u;
    x0 += x1; x1 = rotl32(x1, 17); x1 ^= x0;
    x0 += x1; x1 = rotl32(x1, 29); x1 ^= x0;
    x0 += x1; x1 = rotl32(x1, 16); x1 ^= x0;
    x0 += x1; x1 = rotl32(x1, 24); x1 ^= x0;
    x0 += ks2; x1 += ks0 + 2u;
    x0 += x1; x1 = rotl32(x1, 13); x1 ^= x0;
    x0 += x1; x1 = rotl32(x1, 15); x1 ^= x0;
    x0 += x1; x1 = rotl32(x1, 26); x1 ^= x0;
    x0 += x1; x1 = rotl32(x1, 6);  x1 ^= x0;
    x0 += ks0; x1 += ks1 + 3u;
    x0 += x1; x1 = rotl32(x1, 17); x1 ^= x0;
    x0 += x1; x1 = rotl32(x1, 29); x1 ^= x0;
    x0 += x1; x1 = rotl32(x1, 16); x1 ^= x0;
    x0 += x1; x1 = rotl32(x1, 24); x1 ^= x0;
    x0 += ks1; x1 += ks2 + 4u;
    x0 += x1; x1 = rotl32(x1, 13); x1 ^= x0;
    x0 += x1; x1 = rotl32(x1, 15); x1 ^= x0;
    x0 += x1; x1 = rotl32(x1, 26); x1 ^= x0;
    x0 += x1; x1 = rotl32(x1, 6);  x1 ^= x0;
    x0 += ks2; x1 += ks0 + 5u;
}

// ---------- k_node: register-tiled (TM=8 x TN=4), M=32 nodes/block ----
__global__ __launch_bounds__(128) void k_node(
    const float* __restrict__ x, const float* __restrict__ aerial,
    const float* __restrict__ Wlin, const float* __restrict__ blin,
    const float* __restrict__ Wq, const float* __restrict__ bq,
    const float* __restrict__ Wv, const float* __restrict__ bv,
    float* __restrict__ xl32, float* __restrict__ q32, float* __restrict__ v32) {
    __shared__ float bufA[H_DIM][KN_M + 4];
    __shared__ float bufX[H_DIM][KN_M + 4];
    const int tid = threadIdx.x;
    const int mg = tid >> 5;          // node group 0..3
    const int jj = tid & 31;          // col base 0..31
    const int nb = mg * 8;
    const int n0 = blockIdx.x * KN_M;
    const int c0 = jj, c1 = jj + 32, c2 = jj + 64, c3 = jj + 96;

    for (int m = 0; m < KN_M; ++m)
        bufA[tid][m] = x[(size_t)(n0 + m) * H_DIM + tid];
    __syncthreads();

    // xl = x @ Wlin + blin
    float accL[4][8];
    {
        float b0 = blin[c0], b1 = blin[c1], b2 = blin[c2], b3 = blin[c3];
#pragma unroll
        for (int i = 0; i < 8; ++i) {
            accL[0][i] = b0; accL[1][i] = b1; accL[2][i] = b2; accL[3][i] = b3;
        }
    }
#pragma unroll 4
    for (int k = 0; k < H_DIM; ++k) {
        const float4 xa = *(const float4*)&bufA[k][nb];
        const float4 xb = *(const float4*)&bufA[k][nb + 4];
        const float w0 = Wlin[k * H_DIM + c0];
        const float w1 = Wlin[k * H_DIM + c1];
        const float w2 = Wlin[k * H_DIM + c2];
        const float w3 = Wlin[k * H_DIM + c3];
        const float xv[8] = {xa.x, xa.y, xa.z, xa.w, xb.x, xb.y, xb.z, xb.w};
#pragma unroll
        for (int i = 0; i < 8; ++i) {
            accL[0][i] = fmaf(xv[i], w0, accL[0][i]);
            accL[1][i] = fmaf(xv[i], w1, accL[1][i]);
            accL[2][i] = fmaf(xv[i], w2, accL[2][i]);
            accL[3][i] = fmaf(xv[i], w3, accL[3][i]);
        }
    }
#pragma unroll
    for (int c = 0; c < 4; ++c) {
        const int col = jj + c * 32;
#pragma unroll
        for (int i = 0; i < 8; ++i) {
            xl32[(size_t)(n0 + nb + i) * H_DIM + col] = accL[c][i];
            bufX[col][nb + i] = accL[c][i];
        }
    }
    __syncthreads();

    // v = xl @ Wv + bv  and  q (part 1) = xl @ Wq[0:128] + bq
    float accV[4][8], accQ[4][8];
    {
        float v0 = bv[c0], v1 = bv[c1], v2 = bv[c2], v3 = bv[c3];
        float q0 = bq[c0], q1 = bq[c1], q2 = bq[c2], q3 = bq[c3];
#pragma unroll
        for (int i = 0; i < 8; ++i) {
            accV[0][i] = v0; accV[1][i] = v1; accV[2][i] = v2; accV[3][i] = v3;
            accQ[0][i] = q0; accQ[1][i] = q1; accQ[2][i] = q2; accQ[3][i] = q3;
        }
    }
#pragma unroll 2
    for (int k = 0; k < H_DIM; ++k) {
        const float4 xa = *(const float4*)&bufX[k][nb];
        const float4 xb = *(const float4*)&bufX[k][nb + 4];
        const float wv0 = Wv[k * H_DIM + c0];
        const float wv1 = Wv[k * H_DIM + c1];
        const float wv2 = Wv[k * H_DIM + c2];
        const float wv3 = Wv[k * H_DIM + c3];
        const float wq0 = Wq[k * H_DIM + c0];
        const float wq1 = Wq[k * H_DIM + c1];
        const float wq2 = Wq[k * H_DIM + c2];
        const float wq3 = Wq[k * H_DIM + c3];
        const float xv[8] = {xa.x, xa.y, xa.z, xa.w, xb.x, xb.y, xb.z, xb.w};
#pragma unroll
        for (int i = 0; i < 8; ++i) {
            accV[0][i] = fmaf(xv[i], wv0, accV[0][i]);
            accV[1][i] = fmaf(xv[i], wv1, accV[1][i]);
            accV[2][i] = fmaf(xv[i], wv2, accV[2][i]);
            accV[3][i] = fmaf(xv[i], wv3, accV[3][i]);
            accQ[0][i] = fmaf(xv[i], wq0, accQ[0][i]);
            accQ[1][i] = fmaf(xv[i], wq1, accQ[1][i]);
            accQ[2][i] = fmaf(xv[i], wq2, accQ[2][i]);
            accQ[3][i] = fmaf(xv[i], wq3, accQ[3][i]);
        }
    }
#pragma unroll
    for (int c = 0; c < 4; ++c) {
        const int col = jj + c * 32;
#pragma unroll
        for (int i = 0; i < 8; ++i)
            v32[(size_t)(n0 + nb + i) * H_DIM + col] = accV[c][i];
    }

    // q (part 2): + aerial @ Wq[128:640], staged in 4 chunks of 128 dims
    for (int ch = 0; ch < 4; ++ch) {
        __syncthreads();
        for (int m = 0; m < KN_M; ++m)
            bufA[tid][m] = aerial[(size_t)(n0 + m) * A_DIM + ch * H_DIM + tid];
        __syncthreads();
        const float* Wqc = Wq + (size_t)(H_DIM + ch * H_DIM) * H_DIM;
#pragma unroll 4
        for (int k = 0; k < H_DIM; ++k) {
            const float4 xa = *(const float4*)&bufA[k][nb];
            const float4 xb = *(const float4*)&bufA[k][nb + 4];
            const float w0 = Wqc[k * H_DIM + c0];
            const float w1 = Wqc[k * H_DIM + c1];
            const float w2 = Wqc[k * H_DIM + c2];
            const float w3 = Wqc[k * H_DIM + c3];
            const float xv[8] = {xa.x, xa.y, xa.z, xa.w, xb.x, xb.y, xb.z, xb.w};
#pragma unroll
            for (int i = 0; i < 8; ++i) {
                accQ[0][i] = fmaf(xv[i], w0, accQ[0][i]);
                accQ[1][i] = fmaf(xv[i], w1, accQ[1][i]);
                accQ[2][i] = fmaf(xv[i], w2, accQ[2][i]);
                accQ[3][i] = fmaf(xv[i], w3, accQ[3][i]);
            }
        }
    }
#pragma unroll
    for (int c = 0; c < 4; ++c) {
        const int col = jj + c * 32;
#pragma unroll
        for (int i = 0; i < 8; ++i)
            q32[(size_t)(n0 + nb + i) * H_DIM + col] = accQ[c][i];
    }
}

// dist_q = dist_table @ Wq[640:768]
__global__ __launch_bounds__(128) void k_dist(
    const float* __restrict__ dtab, const float* __restrict__ Wq,
    float* __restrict__ dq32) {
    __shared__ float dsT[H_DIM][8];
    const int j = threadIdx.x;
    const int n0 = blockIdx.x * 8;
#pragma unroll
    for (int m = 0; m < 8; ++m) dsT[j][m] = dtab[(size_t)(n0 + m) * H_DIM + j];
    __syncthreads();
    float acc[8];
#pragma unroll
    for (int m = 0; m < 8; ++m) acc[m] = 0.0f;
    for (int k = 0; k < H_DIM; ++k) {
        float w = Wq[(size_t)(H_DIM + A_DIM + k) * H_DIM + j];
        const float4* xp = (const float4*)&dsT[k][0];
        float4 a0 = xp[0], a1 = xp[1];
        acc[0] = fmaf(a0.x, w, acc[0]); acc[1] = fmaf(a0.y, w, acc[1]);
        acc[2] = fmaf(a0.z, w, acc[2]); acc[3] = fmaf(a0.w, w, acc[3]);
        acc[4] = fmaf(a1.x, w, acc[4]); acc[5] = fmaf(a1.y, w, acc[5]);
        acc[6] = fmaf(a1.z, w, acc[6]); acc[7] = fmaf(a1.w, w, acc[7]);
    }
#pragma unroll
    for (int m = 0; m < 8; ++m) dq32[(size_t)(n0 + m) * H_DIM + j] = acc[m];
}

__device__ __forceinline__ int bin1_of(float s) {
    float t = (s - LO_F) * SCALE1;
    int b = (int)t;
    return min(max(b, 0), NB1 - 1);
}
__device__ __forceinline__ int bin2_of(float s, int b1) {
    float t = (s - LO_F) * SCALE1;
    float frac = t - (float)b1;
    int b = (int)(frac * (float)NB2);
    return min(max(b, 0), NB2 - 1);
}

// ---------- per-edge score: 4 edges per 32-lane group (MLP x4) ----------
// Epilogue on lanes 0..3 (each lane owns its edge's threefry value) — no
// shfl from inactive lanes (R5 bug: ds_bpermute from EXEC-off lanes is UB).
__global__ __launch_bounds__(256) void k_score(
    const int* __restrict__ ei, const int* __restrict__ dist,
    const float* __restrict__ q32, const float* __restrict__ v32,
    const float* __restrict__ dq32,
    unsigned long long* __restrict__ keys, float* __restrict__ s32o) {
    const int half = threadIdx.x >> 5, lane = threadIdx.x & 31;
    const int e0 = blockIdx.x * 32 + half * 4;
    int sidx[4], tidx[4], db[4];
#pragma unroll
    for (int i = 0; i < 4; ++i) {
        sidx[i] = ei[e0 + i];
        tidx[i] = ei[E_EDGES + e0 + i];
        db[i] = dist[e0 + i] / 50;
    }
    // issue all 12 gathers before any use
    float4 q[4], v[4], d[4];
#pragma unroll
    for (int i = 0; i < 4; ++i)
        q[i] = ((const float4*)(q32 + (size_t)sidx[i] * H_DIM))[lane];
#pragma unroll
    for (int i = 0; i < 4; ++i)
        v[i] = ((const float4*)(v32 + (size_t)tidx[i] * H_DIM))[lane];
#pragma unroll
    for (int i = 0; i < 4; ++i)
        d[i] = ((const float4*)(dq32 + (size_t)db[i] * H_DIM))[lane];
    // threefry for edge e0+(lane&3): lane i (i<4) owns edge e0+i's uniform
    uint32_t r0 = 0u, r1 = (uint32_t)(e0 + (lane & 3));
    threefry2x32(0u, 42u, r0, r1);
    uint32_t fb = ((r0 ^ r1) >> 9) | 0x3f800000u;
    float uu_l = __uint_as_float(fb) - 1.0f;

    float ss[4];
#pragma unroll
    for (int i = 0; i < 4; ++i) {
        float dx = q[i].x + d[i].x - v[i].x;
        float dy = q[i].y + d[i].y - v[i].y;
        float dz = q[i].z + d[i].z - v[i].z;
        float dw = q[i].w + d[i].w - v[i].w;
        float t = fmaf(dx, dx, fmaf(dy, dy, fmaf(dz, dz, dw * dw)));
#pragma unroll
        for (int o = 16; o > 0; o >>= 1) t += __shfl_xor(t, o, 64);
        ss[i] = t;
    }
    if (lane < 4) {
        float myss = ss[0];
        if (lane == 1) myss = ss[1];
        if (lane == 2) myss = ss[2];
        if (lane == 3) myss = ss[3];
        float nrm = sqrtf(myss);
        float a = -logf(uu_l + 1e-20f);
        float g = -logf(a + 1e-20f);
        float score = g - nrm;
        int ib = __float_as_int(score);
        unsigned m32 = (ib < 0) ? ~(unsigned)ib : ((unsigned)ib | 0x80000000u);
        const int e = e0 + lane;
        keys[e] = ((unsigned long long)m32 << 32) |
                  (unsigned)(0xFFFFFFFFu - (unsigned)e);
        s32o[e] = score;
    }
}

__global__ __launch_bounds__(256) void k_hist1(const float* __restrict__ s32,
                                               unsigned* __restrict__ hist1) {
    int e = blockIdx.x * 256 + threadIdx.x;
    if (e >= E_EDGES) return;
    atomicAdd(&hist1[bin1_of(s32[e])], 1u);
}

__global__ __launch_bounds__(256) void k_hist2(const float* __restrict__ s32,
                                               const SelState* __restrict__ st,
                                               unsigned* __restrict__ hist2) {
    int e = blockIdx.x * 256 + threadIdx.x;
    if (e >= E_EDGES) return;
    float s = s32[e];
    int b1 = bin1_of(s);
    if (b1 != st->b1) return;
    atomicAdd(&hist2[bin2_of(s, b1)], 1u);
}

// descending scan over 16384 bins to locate the bin holding the target rank
__global__ __launch_bounds__(256) void k_scan(const unsigned* __restrict__ hist,
                                              SelState* st, int phase) {
    __shared__ unsigned csum[256];
    __shared__ unsigned bins[64];
    __shared__ int selc;
    __shared__ unsigned cumbase;
    const int t = threadIdx.x;
    const unsigned target = (phase == 1) ? K_SEL : st->r1;
    unsigned s = 0;
    for (int i = 0; i < 64; ++i) s += hist[t * 64 + i];
    csum[t] = s;
    __syncthreads();
    if (t == 0) {
        unsigned cum = 0; int c = 255;
        for (; c >= 0; --c) {
            if (cum + csum[c] >= target) break;
            cum += csum[c];
        }
        selc = c; cumbase = cum;
    }
    __syncthreads();
    if (t < 64) bins[t] = hist[selc * 64 + t];
    __syncthreads();
    if (t == 0) {
        unsigned cum = cumbase; int b = -1;
        for (int i = 63; i >= 0; --i) {
            if (cum + bins[i] >= target) { b = selc * 64 + i; break; }
            cum += bins[i];
        }
        unsigned r = target - cum;
        if (phase == 1) { st->b1 = b; st->cum1 = cum; st->r1 = r; }
        else           { st->b2 = b; st->cum2 = cum; st->r2 = r; }
    }
}

__global__ __launch_bounds__(256) void k_collect(
    const float* __restrict__ s32, const unsigned long long* __restrict__ keys,
    const SelState* __restrict__ st, unsigned long long* __restrict__ cand,
    unsigned* __restrict__ cnt) {
    int e = blockIdx.x * 256 + threadIdx.x;
    if (e >= E_EDGES) return;
    float s = s32[e];
    int b1 = bin1_of(s);
    if (b1 != st->b1) return;
    if (bin2_of(s, b1) != st->b2) return;
    unsigned p = atomicAdd(cnt, 1u);
    if (p < CAND_MAX) cand[p] = keys[e];
}

// T = r2-th largest key among candidates (keys are unique)
__global__ __launch_bounds__(256) void k_thresh(
    const unsigned long long* __restrict__ cand, const unsigned* __restrict__ cnt,
    SelState* st) {
    int c = (int)min(*cnt, (unsigned)CAND_MAX);
    unsigned r2 = st->r2;
    for (int i = threadIdx.x; i < c; i += blockDim.x) {
        unsigned long long ki = cand[i];
        unsigned g = 0;
        for (int j = 0; j < c; ++j) g += (cand[j] > ki);
        if (g == r2 - 1) st->T = ki;
    }
}

// wave per edge: key >= T selects; scatter xl[src] into msg[tgt] + deg
__global__ __launch_bounds__(256) void k_scatter(
    const int* __restrict__ ei, const unsigned long long* __restrict__ keys,
    const SelState* __restrict__ st, const float* __restrict__ xl32,
    float* __restrict__ msg, float* __restrict__ deg) {
    const int wid = threadIdx.x >> 6, lane = threadIdx.x & 63;
    const int e = blockIdx.x * 4 + wid;
    if (keys[e] >= st->T) {
        int sidx = ei[e], tidx = ei[E_EDGES + e];
        const float* xp = xl32 + (size_t)sidx * H_DIM;
        float* mp = msg + (size_t)tidx * H_DIM;
        const int h = lane * 2;
        atomicAdd(&mp[h], xp[h]);
        atomicAdd(&mp[h + 1], xp[h + 1]);
        if (lane == 0) atomicAdd(&deg[tidx], 1.0f);
    }
}

// out = (msg/max(deg,1)) @ Wl + bl + xl @ Wr
__global__ __launch_bounds__(128) void k_out(
    const float* __restrict__ msg, const float* __restrict__ deg,
    const float* __restrict__ xl32, const float* __restrict__ Wl,
    const float* __restrict__ bl, const float* __restrict__ Wr,
    float* __restrict__ out) {
    __shared__ float axT[H_DIM][8];
    __shared__ float xxT[H_DIM][8];
    const int j = threadIdx.x;
    const int n0 = blockIdx.x * 8;
#pragma unroll
    for (int m = 0; m < 8; ++m) {
        float d = fmaxf(deg[n0 + m], 1.0f);
        axT[j][m] = msg[(size_t)(n0 + m) * H_DIM + j] / d;
        xxT[j][m] = xl32[(size_t)(n0 + m) * H_DIM + j];
    }
    __syncthreads();
    float acc[8];
    float bj = bl[j];
#pragma unroll
    for (int m = 0; m < 8; ++m) acc[m] = bj;
    for (int k = 0; k < H_DIM; ++k) {
        float wl = Wl[k * H_DIM + j];
        float wr = Wr[k * H_DIM + j];
        const float4* ap = (const float4*)&axT[k][0];
        const float4* xp = (const float4*)&xxT[k][0];
        float4 a0 = ap[0], a1 = ap[1];
        float4 x0 = xp[0], x1 = xp[1];
        acc[0] = fmaf(a0.x, wl, fmaf(x0.x, wr, acc[0]));
        acc[1] = fmaf(a0.y, wl, fmaf(x0.y, wr, acc[1]));
        acc[2] = fmaf(a0.z, wl, fmaf(x0.z, wr, acc[2]));
        acc[3] = fmaf(a0.w, wl, fmaf(x0.w, wr, acc[3]));
        acc[4] = fmaf(a1.x, wl, fmaf(x1.x, wr, acc[4]));
        acc[5] = fmaf(a1.y, wl, fmaf(x1.y, wr, acc[5]));
        acc[6] = fmaf(a1.z, wl, fmaf(x1.z, wr, acc[6]));
        acc[7] = fmaf(a1.w, wl, fmaf(x1.w, wr, acc[7]));
    }
#pragma unroll
    for (int m = 0; m < 8; ++m) out[(size_t)(n0 + m) * H_DIM + j] = acc[m];
}

extern "C" void kernel_launch(void* const* d_in, const int* in_sizes, int n_in,
                              void* d_out, int out_size, void* d_ws, size_t ws_size,
                              hipStream_t stream) {
    const float* x      = (const float*)d_in[0];
    const int*   ei     = (const int*)d_in[1];
    const int*   dist   = (const int*)d_in[2];
    const float* aerial = (const float*)d_in[3];
    const float* Wlin   = (const float*)d_in[4];
    const float* blin   = (const float*)d_in[5];
    const float* Wq     = (const float*)d_in[6];
    const float* bq     = (const float*)d_in[7];
    const float* Wv     = (const float*)d_in[8];
    const float* bv     = (const float*)d_in[9];
    const float* dtab   = (const float*)d_in[10];
    const float* Wl     = (const float*)d_in[11];
    const float* bl     = (const float*)d_in[12];
    const float* Wr     = (const float*)d_in[13];
    float* out = (float*)d_out;

    char* ws = (char*)d_ws;
    size_t off = 0;
    auto alloc = [&](size_t bytes) -> void* {
        void* p = ws + off;
        off += (bytes + 255) & ~(size_t)255;
        return p;
    };
    float* q32  = (float*)alloc((size_t)N_NODES * H_DIM * 4);
    float* v32  = (float*)alloc((size_t)N_NODES * H_DIM * 4);
    float* dq32 = (float*)alloc((size_t)NEMB_N * H_DIM * 4);
    unsigned long long* keys = (unsigned long long*)alloc((size_t)E_EDGES * 8);
    float* xl32 = (float*)alloc((size_t)N_NODES * H_DIM * 4);
    float* s32  = (float*)alloc((size_t)E_EDGES * 4);
    char* zbase = ws + off;
    float* msg  = (float*)alloc((size_t)N_NODES * H_DIM * 4);
    float* deg  = (float*)alloc((size_t)N_NODES * 4);
    unsigned* hist1 = (unsigned*)alloc((size_t)NB1 * 4);
    unsigned* hist2 = (unsigned*)alloc((size_t)NB2 * 4);
    unsigned long long* cand = (unsigned long long*)alloc((size_t)CAND_MAX * 8);
    unsigned* counters = (unsigned*)alloc(256);   // [0]=candCount
    SelState* st = (SelState*)alloc(256);
    size_t zlen = (size_t)((ws + off) - zbase);

    hipMemsetAsync(zbase, 0, zlen, stream);

    k_node<<<N_NODES / KN_M, 128, 0, stream>>>(x, aerial, Wlin, blin, Wq, bq, Wv, bv,
                                               xl32, q32, v32);
    k_dist<<<NEMB_N / 8, 128, 0, stream>>>(dtab, Wq, dq32);
    k_score<<<E_EDGES / 32, 256, 0, stream>>>(ei, dist, q32, v32, dq32, keys, s32);
    k_hist1<<<(E_EDGES + 255) / 256, 256, 0, stream>>>(s32, hist1);
    k_scan<<<1, 256, 0, stream>>>(hist1, st, 1);
    k_hist2<<<(E_EDGES + 255) / 256, 256, 0, stream>>>(s32, st, hist2);
    k_scan<<<1, 256, 0, stream>>>(hist2, st, 2);
    k_collect<<<(E_EDGES + 255) / 256, 256, 0, stream>>>(s32, keys, st, cand, &counters[0]);
    k_thresh<<<1, 256, 0, stream>>>(cand, &counters[0], st);
    k_scatter<<<E_EDGES / 4, 256, 0, stream>>>(ei, keys, st, xl32, msg, deg);
    k_out<<<N_NODES / 8, 128, 0, stream>>>(msg, deg, xl32, Wl, bl, Wr, out);
}